// Round 2
// baseline (807.953 us; speedup 1.0000x reference)
//
#include <hip/hip_runtime.h>

#define NN 100000
#define NE 1600000
#define IC 128
#define HID 32
#define NB 782          // buckets of 128 nodes: ceil(100000/128)
#define EB 4096         // edges per passA block
#define NBA 391         // ceil(NE/EB)

// ---------------- edge dtype detection ----------------
__global__ void detect_kernel(const void* ei, int* flag) {
    const long long* p = (const long long*)ei;
    int ok = 1;
    for (int i = 0; i < 64; i++) {
        long long v = p[i];
        if (v < 0 || v >= NN) ok = 0;
    }
    *flag = ok;
}

__device__ __forceinline__ int edge_at(const void* ei, int i64f, long long idx) {
    return i64f ? (int)((const long long*)ei)[idx] : ((const int*)ei)[idx];
}

__global__ void zero_kernel(int* bucketCnt) {
    int t = threadIdx.x;
    if (t < NB) bucketCnt[t] = 0;
}

// Fold w1b@w2a, b1b@w2a, w2b@w3, b2b@w3 into combined operators.
__global__ void precompute_kernel(const float* __restrict__ w1b, const float* __restrict__ b1b,
                                  const float* __restrict__ w2a, const float* __restrict__ w2b,
                                  const float* __restrict__ b2b, const float* __restrict__ w3,
                                  float* Wc, float* bc1, float* wc2, float* c0) {
    int t = threadIdx.x;           // 1024 threads
    int k = t >> 5, j = t & 31;
    float acc = 0.f;
    for (int m = 0; m < HID; m++) acc += w1b[k * HID + m] * w2a[m * HID + j];
    Wc[k * HID + j] = acc;
    if (t < 32) {
        float a = 0.f;
        for (int m = 0; m < HID; m++) a += b1b[m] * w2a[m * HID + t];
        bc1[t] = a;
    } else if (t < 64) {
        int kk = t - 32;
        float a = 0.f;
        for (int jj = 0; jj < HID; jj++) a += w2b[kk * HID + jj] * w3[jj];
        wc2[kk] = a;
    } else if (t == 64) {
        float a = 0.f;
        for (int jj = 0; jj < HID; jj++) a += b2b[jj] * w3[jj];
        *c0 = a;
    }
}

// ---------------- proj1: y1 = x @ w1a  (100000x128 @ 128x32, fp32) ----------------
__global__ __launch_bounds__(256) void proj1_kernel(const float* __restrict__ x,
                                                    const float* __restrict__ w1a,
                                                    float* __restrict__ y1) {
    __shared__ float xs[64 * 132];
    __shared__ float ws[IC * HID];
    int t = threadIdx.x;
    int base = blockIdx.x * 64;

    #pragma unroll
    for (int i = 0; i < 16; i++) ws[i * 256 + t] = w1a[i * 256 + t];

    const float4* xg = (const float4*)x;
    #pragma unroll
    for (int i = 0; i < 8; i++) {
        int fi = i * 256 + t;
        int row = fi >> 5;
        int kq = fi & 31;
        float4 v = make_float4(0.f, 0.f, 0.f, 0.f);
        if (base + row < NN) v = xg[(size_t)(base + row) * 32 + kq];
        *(float4*)&xs[row * 132 + kq * 4] = v;
    }
    __syncthreads();

    int ng = t >> 3;
    int fg = t & 7;
    int n0 = ng * 2, n1 = n0 + 1;
    int j0 = fg * 4;
    float4 a0 = make_float4(0.f, 0.f, 0.f, 0.f);
    float4 a1 = make_float4(0.f, 0.f, 0.f, 0.f);
    #pragma unroll 8
    for (int k = 0; k < IC; k++) {
        float x0 = xs[n0 * 132 + k];
        float x1 = xs[n1 * 132 + k];
        float4 w = *(const float4*)&ws[k * HID + j0];
        a0.x += x0 * w.x; a0.y += x0 * w.y; a0.z += x0 * w.z; a0.w += x0 * w.w;
        a1.x += x1 * w.x; a1.y += x1 * w.y; a1.z += x1 * w.z; a1.w += x1 * w.w;
    }
    if (base + n0 < NN) ((float4*)y1)[(size_t)(base + n0) * 8 + fg] = a0;
    if (base + n1 < NN) ((float4*)y1)[(size_t)(base + n1) * 8 + fg] = a1;
}

// ---------------- bucket histogram (pass A0) ----------------
__global__ __launch_bounds__(256) void hist_kernel(const void* ei, const int* flag,
                                                   int* bucketCnt) {
    __shared__ int h[NB];
    int t = threadIdx.x;
    for (int b = t; b < NB; b += 256) h[b] = 0;
    __syncthreads();
    int i64f = *flag;
    long long ebase = (long long)blockIdx.x * EB;
    for (int i = t; i < EB; i += 256) {
        long long e = ebase + i;
        if (e < NE) {
            int d = edge_at(ei, i64f, NE + e);
            atomicAdd(&h[d >> 7], 1);
        }
    }
    __syncthreads();
    for (int b = t; b < NB; b += 256) if (h[b]) atomicAdd(&bucketCnt[b], h[b]);
}

// ---------------- bucket scan (one block) ----------------
__global__ __launch_bounds__(1024) void scanb_kernel(const int* __restrict__ bucketCnt,
                                                     int* __restrict__ bucketBase,
                                                     int* __restrict__ gcursor) {
    __shared__ int sh[1024];
    int t = threadIdx.x;
    int v = (t < NB) ? bucketCnt[t] : 0;
    sh[t] = v;
    __syncthreads();
    for (int off = 1; off < 1024; off <<= 1) {
        int a = (t >= off) ? sh[t - off] : 0;
        __syncthreads();
        sh[t] += a;
        __syncthreads();
    }
    if (t < NB) {
        int excl = sh[t] - v;
        bucketBase[t] = excl;
        gcursor[t] = excl;
    }
    if (t == 0) bucketBase[NB] = NE;
}

// ---------------- pass A: bin edges into bucket regions ----------------
// packed word: (src << 7) | (dst & 127)
__global__ __launch_bounds__(256) void binscatter_kernel(const void* ei, const int* flag,
                                                         int* gcursor,
                                                         unsigned int* __restrict__ binned) {
    __shared__ int raws[EB];
    __shared__ int rawd[EB];
    __shared__ int h[NB];
    __shared__ int lcur[NB];
    int t = threadIdx.x;
    for (int b = t; b < NB; b += 256) h[b] = 0;
    __syncthreads();
    int i64f = *flag;
    long long ebase = (long long)blockIdx.x * EB;
    for (int i = t; i < EB; i += 256) {
        long long e = ebase + i;
        int s = 0, d = -1;
        if (e < NE) {
            s = edge_at(ei, i64f, e);
            d = edge_at(ei, i64f, NE + e);
            atomicAdd(&h[d >> 7], 1);
        }
        raws[i] = s;
        rawd[i] = d;
    }
    __syncthreads();
    for (int b = t; b < NB; b += 256) {
        lcur[b] = h[b] ? atomicAdd(&gcursor[b], h[b]) : 0;
    }
    __syncthreads();
    for (int i = t; i < EB; i += 256) {
        int d = rawd[i];
        if (d >= 0) {
            int b = d >> 7;
            int pos = atomicAdd(&lcur[b], 1);
            binned[pos] = ((unsigned)raws[i] << 7) | (unsigned)(d & 127);
        }
    }
}

// ---------------- layer1: bucket aggregate + fused MLP ----------------
// y2 = relu(y1 + A y1 + b1a) @ Wc + bc1
__global__ __launch_bounds__(256) void agg_mlp1_kernel(const float* __restrict__ y1,
                                                       const int* __restrict__ bucketBase,
                                                       const unsigned int* __restrict__ binned,
                                                       const float* __restrict__ b1a,
                                                       const float* __restrict__ Wc,
                                                       const float* __restrict__ bc1,
                                                       float* __restrict__ y2) {
    __shared__ float acc[128 * 33];
    __shared__ float Wl[HID * HID];
    __shared__ float b1l[HID];
    __shared__ float bcl[HID];
    int t = threadIdx.x;
    #pragma unroll
    for (int i = 0; i < 4; i++) Wl[i * 256 + t] = Wc[i * 256 + t];
    if (t < HID) { b1l[t] = b1a[t]; bcl[t] = bc1[t]; }

    int b = blockIdx.x;
    int nbase = b << 7;
    for (int i = t; i < 128 * 32; i += 256) {
        int node = i >> 5, f = i & 31;
        int gn = nbase + node;
        acc[node * 33 + f] = (gn < NN) ? y1[(size_t)gn * 32 + f] : 0.f;
    }
    __syncthreads();

    int ebeg = bucketBase[b], eend = bucketBase[b + 1];
    int lane8 = t & 7;
    int grp = t >> 3;
    const float4* y1v = (const float4*)y1;
    for (int p = ebeg + grp; p < eend; p += 32) {
        unsigned v = binned[p];
        int src = v >> 7;
        int dl = v & 127;
        float4 g = y1v[(size_t)src * 8 + lane8];
        float* a = &acc[dl * 33 + lane8 * 4];
        atomicAdd(a + 0, g.x);
        atomicAdd(a + 1, g.y);
        atomicAdd(a + 2, g.z);
        atomicAdd(a + 3, g.w);
    }
    __syncthreads();

    int f = t & 31;
    int sub = t >> 5;   // 0..7
    for (int p = 0; p < 16; p++) {
        int node = p * 8 + sub;
        int gn = nbase + node;
        float u = acc[node * 33 + f] + b1l[f];
        u = u > 0.f ? u : 0.f;
        float o = bcl[f];
        #pragma unroll
        for (int k = 0; k < HID; k++) {
            o += __shfl(u, k, 32) * Wl[k * HID + f];
        }
        if (gn < NN) y2[(size_t)gn * 32 + f] = o;
    }
}

// ---------------- layer2: bucket aggregate + fused dot ----------------
// s = relu(y2 + A y2 + b2a) . wc2 + c0
__global__ __launch_bounds__(256) void agg_mlp2_kernel(const float* __restrict__ y2,
                                                       const int* __restrict__ bucketBase,
                                                       const unsigned int* __restrict__ binned,
                                                       const float* __restrict__ b2a,
                                                       const float* __restrict__ wc2,
                                                       const float* __restrict__ c0,
                                                       float* __restrict__ sbuf) {
    __shared__ float acc[128 * 33];
    __shared__ float wcl[HID];
    __shared__ float b2l[HID];
    int t = threadIdx.x;
    if (t < HID) { wcl[t] = wc2[t]; b2l[t] = b2a[t]; }

    int b = blockIdx.x;
    int nbase = b << 7;
    for (int i = t; i < 128 * 32; i += 256) {
        int node = i >> 5, f = i & 31;
        int gn = nbase + node;
        acc[node * 33 + f] = (gn < NN) ? y2[(size_t)gn * 32 + f] : 0.f;
    }
    __syncthreads();

    int ebeg = bucketBase[b], eend = bucketBase[b + 1];
    int lane8 = t & 7;
    int grp = t >> 3;
    const float4* y2v = (const float4*)y2;
    for (int p = ebeg + grp; p < eend; p += 32) {
        unsigned v = binned[p];
        int src = v >> 7;
        int dl = v & 127;
        float4 g = y2v[(size_t)src * 8 + lane8];
        float* a = &acc[dl * 33 + lane8 * 4];
        atomicAdd(a + 0, g.x);
        atomicAdd(a + 1, g.y);
        atomicAdd(a + 2, g.z);
        atomicAdd(a + 3, g.w);
    }
    __syncthreads();

    float cc0 = *c0;
    int f = t & 31;
    int sub = t >> 5;
    for (int p = 0; p < 16; p++) {
        int node = p * 8 + sub;
        int gn = nbase + node;
        float u = acc[node * 33 + f] + b2l[f];
        u = u > 0.f ? u : 0.f;
        float tt = u * wcl[f];
        #pragma unroll
        for (int off = 16; off > 0; off >>= 1) tt += __shfl_xor(tt, off, 32);
        if (f == 0 && gn < NN) sbuf[gn] = tt + cc0;
    }
}

// ---------------- layer3: scalar bucket aggregate ----------------
// out = s + A s + b3
__global__ __launch_bounds__(256) void agg3_kernel(const float* __restrict__ sbuf,
                                                   const int* __restrict__ bucketBase,
                                                   const unsigned int* __restrict__ binned,
                                                   const float* __restrict__ b3,
                                                   float* __restrict__ out) {
    __shared__ float sacc[128];
    int t = threadIdx.x;
    int b = blockIdx.x;
    int nbase = b << 7;
    if (t < 128) {
        int gn = nbase + t;
        sacc[t] = (gn < NN) ? sbuf[gn] : 0.f;
    }
    __syncthreads();

    int ebeg = bucketBase[b], eend = bucketBase[b + 1];
    for (int p = ebeg + t; p < eend; p += 256) {
        unsigned v = binned[p];
        int src = v >> 7;
        int dl = v & 127;
        atomicAdd(&sacc[dl], sbuf[src]);
    }
    __syncthreads();

    if (t < 128) {
        int gn = nbase + t;
        if (gn < NN) out[gn] = sacc[t] + b3[0];
    }
}

// ---------------- host ----------------
extern "C" void kernel_launch(void* const* d_in, const int* in_sizes, int n_in,
                              void* d_out, int out_size, void* d_ws, size_t ws_size,
                              hipStream_t stream) {
    const float* x   = (const float*)d_in[0];
    const void*  ei  = d_in[1];
    const float* w1a = (const float*)d_in[2];
    const float* b1a = (const float*)d_in[3];
    const float* w1b = (const float*)d_in[4];
    const float* b1b = (const float*)d_in[5];
    const float* w2a = (const float*)d_in[6];
    const float* b2a = (const float*)d_in[7];
    const float* w2b = (const float*)d_in[8];
    const float* b2b = (const float*)d_in[9];
    const float* w3  = (const float*)d_in[10];
    const float* b3  = (const float*)d_in[11];
    float* out = (float*)d_out;

    char* w = (char*)d_ws;
    float*        y1         = (float*)(w + 0);            // 12,800,000
    float*        y2         = (float*)(w + 12800000);     // 12,800,000
    float*        sbuf       = (float*)(w + 25600000);     //    400,000
    unsigned int* binned     = (unsigned int*)(w + 26000000); // 6,400,000
    int*          bucketCnt  = (int*)(w + 32400000);       //      3,128
    int*          bucketBase = (int*)(w + 32403200);       //      3,132
    int*          gcursor    = (int*)(w + 32406400);       //      3,128
    int*          flag       = (int*)(w + 32409600);       //         16
    float*        Wc         = (float*)(w + 32409664);     //      4,096
    float*        bc1        = (float*)(w + 32413760);     //        128
    float*        wc2        = (float*)(w + 32413888);     //        128
    float*        c0         = (float*)(w + 32414016);     //         16

    detect_kernel<<<1, 1, 0, stream>>>(ei, flag);
    zero_kernel<<<1, 1024, 0, stream>>>(bucketCnt);
    precompute_kernel<<<1, 1024, 0, stream>>>(w1b, b1b, w2a, w2b, b2b, w3, Wc, bc1, wc2, c0);
    proj1_kernel<<<(NN + 63) / 64, 256, 0, stream>>>(x, w1a, y1);

    hist_kernel<<<NBA, 256, 0, stream>>>(ei, flag, bucketCnt);
    scanb_kernel<<<1, 1024, 0, stream>>>(bucketCnt, bucketBase, gcursor);
    binscatter_kernel<<<NBA, 256, 0, stream>>>(ei, flag, gcursor, binned);

    agg_mlp1_kernel<<<NB, 256, 0, stream>>>(y1, bucketBase, binned, b1a, Wc, bc1, y2);
    agg_mlp2_kernel<<<NB, 256, 0, stream>>>(y2, bucketBase, binned, b2a, wc2, c0, sbuf);
    agg3_kernel<<<NB, 256, 0, stream>>>(sbuf, bucketBase, binned, b3, out);
}

// Round 3
// 253.873 us; speedup vs baseline: 3.1825x; 3.1825x over previous
//
#include <hip/hip_runtime.h>

#define NN 100000
#define NE 1600000
#define IC 128
#define HID 32
#define NB 782          // buckets of 128 nodes
#define EB 4096         // edges per binning block
#define NBA 391         // ceil(NE/EB)

// ---------------- edge dtype detection ----------------
__global__ void detect_kernel(const void* ei, int* flag) {
    const long long* p = (const long long*)ei;
    int ok = 1;
    for (int i = 0; i < 64; i++) {
        long long v = p[i];
        if (v < 0 || v >= NN) ok = 0;
    }
    *flag = ok;
}

__device__ __forceinline__ int edge_at(const void* ei, int i64f, long long idx) {
    return i64f ? (int)((const long long*)ei)[idx] : ((const int*)ei)[idx];
}

__global__ void zero_kernel(int* bucketCnt) {
    int t = threadIdx.x;
    if (t < NB) bucketCnt[t] = 0;
}

// Fold w1b@w2a, b1b@w2a, w2b@w3, b2b@w3.
__global__ void precompute_kernel(const float* __restrict__ w1b, const float* __restrict__ b1b,
                                  const float* __restrict__ w2a, const float* __restrict__ w2b,
                                  const float* __restrict__ b2b, const float* __restrict__ w3,
                                  float* Wc, float* bc1, float* wc2, float* c0) {
    int t = threadIdx.x;           // 1024 threads
    int k = t >> 5, j = t & 31;
    float acc = 0.f;
    for (int m = 0; m < HID; m++) acc += w1b[k * HID + m] * w2a[m * HID + j];
    Wc[k * HID + j] = acc;
    if (t < 32) {
        float a = 0.f;
        for (int m = 0; m < HID; m++) a += b1b[m] * w2a[m * HID + t];
        bc1[t] = a;
    } else if (t < 64) {
        int kk = t - 32;
        float a = 0.f;
        for (int jj = 0; jj < HID; jj++) a += w2b[kk * HID + jj] * w3[jj];
        wc2[kk] = a;
    } else if (t == 64) {
        float a = 0.f;
        for (int jj = 0; jj < HID; jj++) a += b2b[jj] * w3[jj];
        *c0 = a;
    }
}

// ---------------- proj1: y1 = x @ w1a ----------------
__global__ __launch_bounds__(256) void proj1_kernel(const float* __restrict__ x,
                                                    const float* __restrict__ w1a,
                                                    float* __restrict__ y1) {
    __shared__ float xs[64 * 132];
    __shared__ float ws[IC * HID];
    int t = threadIdx.x;
    int base = blockIdx.x * 64;

    #pragma unroll
    for (int i = 0; i < 16; i++) ws[i * 256 + t] = w1a[i * 256 + t];

    const float4* xg = (const float4*)x;
    #pragma unroll
    for (int i = 0; i < 8; i++) {
        int fi = i * 256 + t;
        int row = fi >> 5;
        int kq = fi & 31;
        float4 v = make_float4(0.f, 0.f, 0.f, 0.f);
        if (base + row < NN) v = xg[(size_t)(base + row) * 32 + kq];
        *(float4*)&xs[row * 132 + kq * 4] = v;
    }
    __syncthreads();

    int ng = t >> 3;
    int fg = t & 7;
    int n0 = ng * 2, n1 = n0 + 1;
    int j0 = fg * 4;
    float4 a0 = make_float4(0.f, 0.f, 0.f, 0.f);
    float4 a1 = make_float4(0.f, 0.f, 0.f, 0.f);
    #pragma unroll 8
    for (int k = 0; k < IC; k++) {
        float x0 = xs[n0 * 132 + k];
        float x1 = xs[n1 * 132 + k];
        float4 w = *(const float4*)&ws[k * HID + j0];
        a0.x += x0 * w.x; a0.y += x0 * w.y; a0.z += x0 * w.z; a0.w += x0 * w.w;
        a1.x += x1 * w.x; a1.y += x1 * w.y; a1.z += x1 * w.z; a1.w += x1 * w.w;
    }
    if (base + n0 < NN) ((float4*)y1)[(size_t)(base + n0) * 8 + fg] = a0;
    if (base + n1 < NN) ((float4*)y1)[(size_t)(base + n1) * 8 + fg] = a1;
}

// ---------------- bucket histogram ----------------
__global__ __launch_bounds__(256) void hist_kernel(const void* ei, const int* flag,
                                                   int* bucketCnt) {
    __shared__ int h[NB];
    int t = threadIdx.x;
    for (int b = t; b < NB; b += 256) h[b] = 0;
    __syncthreads();
    int i64f = *flag;
    long long ebase = (long long)blockIdx.x * EB;
    for (int i = t; i < EB; i += 256) {
        long long e = ebase + i;
        if (e < NE) {
            int d = edge_at(ei, i64f, NE + e);
            atomicAdd(&h[d >> 7], 1);
        }
    }
    __syncthreads();
    for (int b = t; b < NB; b += 256) if (h[b]) atomicAdd(&bucketCnt[b], h[b]);
}

// ---------------- bucket scan (one block) ----------------
__global__ __launch_bounds__(1024) void scanb_kernel(const int* __restrict__ bucketCnt,
                                                     int* __restrict__ bucketBase,
                                                     int* __restrict__ gcursor,
                                                     int* __restrict__ rowptr) {
    __shared__ int sh[1024];
    int t = threadIdx.x;
    int v = (t < NB) ? bucketCnt[t] : 0;
    sh[t] = v;
    __syncthreads();
    for (int off = 1; off < 1024; off <<= 1) {
        int a = (t >= off) ? sh[t - off] : 0;
        __syncthreads();
        sh[t] += a;
        __syncthreads();
    }
    if (t < NB) {
        int excl = sh[t] - v;
        bucketBase[t] = excl;
        gcursor[t] = excl;
    }
    if (t == 0) { bucketBase[NB] = NE; rowptr[NN] = NE; }
}

// ---------------- bin edges into bucket regions ----------------
// packed word: (src << 7) | (dst & 127)
__global__ __launch_bounds__(256) void binscatter_kernel(const void* ei, const int* flag,
                                                         int* gcursor,
                                                         unsigned int* __restrict__ binned) {
    __shared__ int raws[EB];
    __shared__ int rawd[EB];
    __shared__ int h[NB];
    __shared__ int lcur[NB];
    int t = threadIdx.x;
    for (int b = t; b < NB; b += 256) h[b] = 0;
    __syncthreads();
    int i64f = *flag;
    long long ebase = (long long)blockIdx.x * EB;
    for (int i = t; i < EB; i += 256) {
        long long e = ebase + i;
        int s = 0, d = -1;
        if (e < NE) {
            s = edge_at(ei, i64f, e);
            d = edge_at(ei, i64f, NE + e);
            atomicAdd(&h[d >> 7], 1);
        }
        raws[i] = s;
        rawd[i] = d;
    }
    __syncthreads();
    for (int b = t; b < NB; b += 256) {
        lcur[b] = h[b] ? atomicAdd(&gcursor[b], h[b]) : 0;
    }
    __syncthreads();
    for (int i = t; i < EB; i += 256) {
        int d = rawd[i];
        if (d >= 0) {
            int b = d >> 7;
            int pos = atomicAdd(&lcur[b], 1);
            binned[pos] = ((unsigned)raws[i] << 7) | (unsigned)(d & 127);
        }
    }
}

// ---------------- per-bucket CSR: sort bucket edges by local node ----------------
__global__ __launch_bounds__(256) void bucket_csr_kernel(const unsigned int* __restrict__ binned,
                                                         const int* __restrict__ bucketBase,
                                                         int* __restrict__ rowptr,
                                                         int* __restrict__ esrc) {
    __shared__ int cnt[128];
    __shared__ int sc[128];
    __shared__ int cur[128];
    int t = threadIdx.x;
    int b = blockIdx.x;
    int ebeg = bucketBase[b], eend = bucketBase[b + 1];
    if (t < 128) cnt[t] = 0;
    __syncthreads();
    for (int p = ebeg + t; p < eend; p += 256)
        atomicAdd(&cnt[binned[p] & 127], 1);
    __syncthreads();
    if (t < 128) sc[t] = cnt[t];
    __syncthreads();
    for (int off = 1; off < 128; off <<= 1) {
        int a = 0;
        if (t < 128 && t >= off) a = sc[t - off];
        __syncthreads();
        if (t < 128) sc[t] += a;
        __syncthreads();
    }
    if (t < 128) {
        int excl = sc[t] - cnt[t];
        int gn = (b << 7) + t;
        if (gn < NN) rowptr[gn] = ebeg + excl;
        cur[t] = excl;
    }
    __syncthreads();
    for (int p = ebeg + t; p < eend; p += 256) {
        unsigned w = binned[p];
        int dl = w & 127;
        int pos = ebeg + atomicAdd(&cur[dl], 1);
        esrc[pos] = w >> 7;
    }
}

// ---------------- layer1: node-parallel aggregate + fused MLP ----------------
// y2 = relu(y1 + A y1 + b1a) @ Wc + bc1 ; one wave per node, halves split edges
__global__ __launch_bounds__(256) void agg_mlp1_kernel(const float* __restrict__ y1,
                                                       const int* __restrict__ rowptr,
                                                       const int* __restrict__ esrc,
                                                       const float* __restrict__ b1a,
                                                       const float* __restrict__ Wc,
                                                       const float* __restrict__ bc1,
                                                       float* __restrict__ y2) {
    __shared__ float Wl[HID * HID];
    __shared__ float b1l[HID];
    __shared__ float bcl[HID];
    int t = threadIdx.x;
    #pragma unroll
    for (int i = 0; i < 4; i++) Wl[i * 256 + t] = Wc[i * 256 + t];
    if (t < HID) { b1l[t] = b1a[t]; bcl[t] = bc1[t]; }
    __syncthreads();

    int wid  = t >> 6;        // wave 0..3
    int half = (t >> 5) & 1;  // half of wave
    int f    = t & 31;
    int n = blockIdx.x * 4 + wid;      // NN = 25000*4 exact

    float v = half ? 0.f : y1[(size_t)n * 32 + f];
    int beg = rowptr[n], end = rowptr[n + 1];
    int p = beg + half;
    for (; p + 2 < end; p += 4) {
        int s0 = esrc[p];
        int s1 = esrc[p + 2];
        float g0 = y1[(size_t)s0 * 32 + f];
        float g1 = y1[(size_t)s1 * 32 + f];
        v += g0;
        v += g1;
    }
    if (p < end) v += y1[(size_t)esrc[p] * 32 + f];

    v += __shfl_xor(v, 32, 64);        // merge halves
    v += b1l[f];
    v = v > 0.f ? v : 0.f;

    float o = bcl[f];
    #pragma unroll
    for (int k = 0; k < HID; k++)
        o += __shfl(v, k, 32) * Wl[k * HID + f];

    if (half == 0) y2[(size_t)n * 32 + f] = o;
}

// ---------------- layer2: node-parallel aggregate + fused dot ----------------
// s = relu(y2 + A y2 + b2a) . wc2 + c0
__global__ __launch_bounds__(256) void agg_mlp2_kernel(const float* __restrict__ y2,
                                                       const int* __restrict__ rowptr,
                                                       const int* __restrict__ esrc,
                                                       const float* __restrict__ b2a,
                                                       const float* __restrict__ wc2,
                                                       const float* __restrict__ c0,
                                                       float* __restrict__ sbuf) {
    __shared__ float wcl[HID];
    __shared__ float b2l[HID];
    int t = threadIdx.x;
    if (t < HID) { wcl[t] = wc2[t]; b2l[t] = b2a[t]; }
    __syncthreads();

    int wid  = t >> 6;
    int half = (t >> 5) & 1;
    int f    = t & 31;
    int n = blockIdx.x * 4 + wid;

    float v = half ? 0.f : y2[(size_t)n * 32 + f];
    int beg = rowptr[n], end = rowptr[n + 1];
    int p = beg + half;
    for (; p + 2 < end; p += 4) {
        int s0 = esrc[p];
        int s1 = esrc[p + 2];
        float g0 = y2[(size_t)s0 * 32 + f];
        float g1 = y2[(size_t)s1 * 32 + f];
        v += g0;
        v += g1;
    }
    if (p < end) v += y2[(size_t)esrc[p] * 32 + f];

    v += __shfl_xor(v, 32, 64);
    v += b2l[f];
    v = v > 0.f ? v : 0.f;
    float tt = v * wcl[f];
    #pragma unroll
    for (int off = 16; off > 0; off >>= 1) tt += __shfl_xor(tt, off, 32);
    if (f == 0 && half == 0) sbuf[n] = tt + *c0;
}

// ---------------- layer3: scalar aggregate ----------------
__global__ __launch_bounds__(256) void final_kernel(const float* __restrict__ sbuf,
                                                    const int* __restrict__ rowptr,
                                                    const int* __restrict__ esrc,
                                                    const float* __restrict__ b3,
                                                    float* __restrict__ out) {
    int n = blockIdx.x * 256 + threadIdx.x;
    if (n >= NN) return;
    float v = sbuf[n] + b3[0];
    int beg = rowptr[n], end = rowptr[n + 1];
    int p = beg;
    for (; p + 4 <= end; p += 4) {
        int s0 = esrc[p], s1 = esrc[p + 1], s2 = esrc[p + 2], s3 = esrc[p + 3];
        float g0 = sbuf[s0], g1 = sbuf[s1], g2 = sbuf[s2], g3 = sbuf[s3];
        v += g0; v += g1; v += g2; v += g3;
    }
    for (; p < end; p++) v += sbuf[esrc[p]];
    out[n] = v;
}

// ---------------- host ----------------
extern "C" void kernel_launch(void* const* d_in, const int* in_sizes, int n_in,
                              void* d_out, int out_size, void* d_ws, size_t ws_size,
                              hipStream_t stream) {
    const float* x   = (const float*)d_in[0];
    const void*  ei  = d_in[1];
    const float* w1a = (const float*)d_in[2];
    const float* b1a = (const float*)d_in[3];
    const float* w1b = (const float*)d_in[4];
    const float* b1b = (const float*)d_in[5];
    const float* w2a = (const float*)d_in[6];
    const float* b2a = (const float*)d_in[7];
    const float* w2b = (const float*)d_in[8];
    const float* b2b = (const float*)d_in[9];
    const float* w3  = (const float*)d_in[10];
    const float* b3  = (const float*)d_in[11];
    float* out = (float*)d_out;

    char* w = (char*)d_ws;
    float*        y1         = (float*)(w + 0);              // 12,800,000
    int*          esrc       = (int*)  (w + 12800000);       //  6,400,000
    int*          rowptr     = (int*)  (w + 19200000);       //    400,016
    float*        sbuf       = (float*)(w + 19600016);       //    400,000
    int*          bucketCnt  = (int*)  (w + 20000016);       //      3,136
    int*          bucketBase = (int*)  (w + 20003152);       //      3,136
    int*          gcursor    = (int*)  (w + 20006288);       //      3,136
    int*          flag       = (int*)  (w + 20009424);       //         16
    float*        Wc         = (float*)(w + 20009440);       //      4,096
    float*        bc1        = (float*)(w + 20013536);       //        128
    float*        wc2        = (float*)(w + 20013664);       //        128
    float*        c0         = (float*)(w + 20013792);       //         16
    // y2 overlays binned (binned dead before agg_mlp1 writes y2)
    unsigned int* binned     = (unsigned int*)(w + 20013808); // 6,400,000
    float*        y2         = (float*)(w + 20013808);        // 12,800,000  (total 32.8 MB)

    detect_kernel<<<1, 1, 0, stream>>>(ei, flag);
    zero_kernel<<<1, 1024, 0, stream>>>(bucketCnt);
    precompute_kernel<<<1, 1024, 0, stream>>>(w1b, b1b, w2a, w2b, b2b, w3, Wc, bc1, wc2, c0);
    proj1_kernel<<<(NN + 63) / 64, 256, 0, stream>>>(x, w1a, y1);

    hist_kernel<<<NBA, 256, 0, stream>>>(ei, flag, bucketCnt);
    scanb_kernel<<<1, 1024, 0, stream>>>(bucketCnt, bucketBase, gcursor, rowptr);
    binscatter_kernel<<<NBA, 256, 0, stream>>>(ei, flag, gcursor, binned);
    bucket_csr_kernel<<<NB, 256, 0, stream>>>(binned, bucketBase, rowptr, esrc);

    agg_mlp1_kernel<<<NN / 4, 256, 0, stream>>>(y1, rowptr, esrc, b1a, Wc, bc1, y2);
    agg_mlp2_kernel<<<NN / 4, 256, 0, stream>>>(y2, rowptr, esrc, b2a, wc2, c0, sbuf);
    final_kernel<<<(NN + 255) / 256, 256, 0, stream>>>(sbuf, rowptr, esrc, b3, out);
}